// Round 17
// baseline (45.759 us; speedup 1.0000x reference)
//
#include <hip/hip_runtime.h>

// OutConv_lstm: 1x1 conv (64ch -> 1) -> bidirectional projected LSTM (HID=5, PROJ=1)
// -> ss = hf+hb -> softmax over seq dim (both output channels identical since
// channel-1 logits are ss-1, a constant shift along the softmax axis).
//
// R17: geometry change only vs R16 — 125 blocks x 512 threads (8 waves:
// 4 per dir, 32 chunks/dir, BLK_EMIT=480). Same 1000 waves total, but:
//  - dispatch ramp halves (28.5 ns/block x 125 = 3.6us vs 7.1us)
//  - 2 waves/SIMD: wave B fills wave A's dependency bubbles (R9: VALUBusy
//    70% at 1 wave/SIMD => ~30% idle issue slots); scan ~787 -> ~600 cy/step
// LDS 63KB static (sx 32.3KB + hb 30.7KB). K1 (wide conv + wbuf prepack)
// and K3 (inline-finalize write) unchanged from R16. WARM=8, 23 steps.

#define L_SEQ 60000
#define NB 8
#define NCH 64
#define HID 5
#define CHUNK 15
#define WARM 8
#define MAXS (WARM + CHUNK)            // 23 iterations
#define BLK_EMIT 480                   // emit span per dir per block (32 chunks)
#define NBLK (L_SEQ / BLK_EMIT)        // 125 blocks
#define WIN 504                        // LDS window (max index used 498)
// wbuf layout (floats): [0..159] v2f weights dir0|dir1 (40 v2f each)
//                       [160..169] wr_f|wr_b  [170..185] h0  [186..265] c0*NT2E
#define WB_WR 160
#define WB_H0 170
#define WB_C0 186

typedef __attribute__((ext_vector_type(2))) float v2f;

__device__ __forceinline__ float fast_exp2(float x) { return __builtin_amdgcn_exp2f(x); }
__device__ __forceinline__ float fast_rcp(float x) { return __builtin_amdgcn_rcpf(x); }
__device__ __forceinline__ float fast_exp(float x) {
  return __builtin_amdgcn_exp2f(x * 1.4426950408889634f);
}
__device__ __forceinline__ v2f fma2(v2f a, v2f b, v2f c) {
  return __builtin_elementwise_fma(a, b, c);
}

#define NL2E (-1.4426950408889634f)   // -log2(e): sigmoid gates
#define NT2E (-2.8853900817779268f)   // -2*log2(e): tanh args

// ---------------- Kernel 1: 1x1 conv + pack + weight prepack ----------------
__global__ __launch_bounds__(256) void conv_pack(
    const float* __restrict__ x, const float* __restrict__ inp,
    const float* __restrict__ cw, const float* __restrict__ cb,
    const float* __restrict__ wih_f, const float* __restrict__ whh_f,
    const float* __restrict__ bih_f, const float* __restrict__ bhh_f,
    const float* __restrict__ whr_f,
    const float* __restrict__ wih_b, const float* __restrict__ whh_b,
    const float* __restrict__ bih_b, const float* __restrict__ bhh_b,
    const float* __restrict__ whr_b,
    const float* __restrict__ h0, const float* __restrict__ c0,
    float2* __restrict__ xp, float* __restrict__ wbuf) {
  // ---- weight/state prepack (block 0 only; disjoint lanes) ----
  if (blockIdx.x == 0) {
    int t = threadIdx.x;
    if (t < 10) {
      int dd = t / 5, m = t - dd * 5;
      const float* wih = dd ? wih_b : wih_f;
      const float* whh = dd ? whh_b : whh_f;
      const float* bih = dd ? bih_b : bih_f;
      const float* bhh = dd ? bhh_b : bhh_f;
      const float* whr = dd ? whr_b : whr_f;
      const int ki = m, kf = 5 + m, kg = 10 + m, ko = 15 + m;
      float2* wd = (float2*)wbuf + dd * 40;
      wd[m]      = make_float2(wih[2 * ki] * NL2E, wih[2 * kf] * NL2E);
      wd[5 + m]  = make_float2(wih[2 * ki + 1] * NL2E, wih[2 * kf + 1] * NL2E);
      wd[10 + m] = make_float2((bih[ki] + bhh[ki]) * NL2E, (bih[kf] + bhh[kf]) * NL2E);
      wd[15 + m] = make_float2(whh[ki] * NL2E, whh[kf] * NL2E);
      wd[20 + m] = make_float2(wih[2 * kg] * NT2E, wih[2 * ko] * NL2E);
      wd[25 + m] = make_float2(wih[2 * kg + 1] * NT2E, wih[2 * ko + 1] * NL2E);
      wd[30 + m] = make_float2((bih[kg] + bhh[kg]) * NT2E, (bih[ko] + bhh[ko]) * NL2E);
      wd[35 + m] = make_float2(whh[kg] * NT2E, whh[ko] * NL2E);
      wbuf[WB_WR + dd * 5 + m] = whr[m];
    } else if (t >= 16 && t < 32) {
      wbuf[WB_H0 + (t - 16)] = h0[t - 16];
    } else if (t >= 32 && t < 112) {
      int i = t - 32;                      // i = (d*NB+b)*HID+m, 0..79
      wbuf[WB_C0 + i] = c0[i] * NT2E;
    }
  }
  // ---- conv main (wide) ----
  int tid = blockIdx.x * 256 + threadIdx.x;
  const int perb = L_SEQ / 4;
  if (tid >= NB * perb) return;
  int b = tid / perb;
  int l0 = (tid - b * perb) * 4;
  const float* xb = x + (size_t)b * NCH * L_SEQ + l0;
  float4 acc = make_float4(0.f, 0.f, 0.f, 0.f);
#pragma unroll 8
  for (int ch = 0; ch < NCH; ++ch) {
    float w = cw[ch];
    const float4 xv = *(const float4*)(xb + (size_t)ch * L_SEQ);
    acc.x = fmaf(w, xv.x, acc.x);
    acc.y = fmaf(w, xv.y, acc.y);
    acc.z = fmaf(w, xv.z, acc.z);
    acc.w = fmaf(w, xv.w, acc.w);
  }
  float bias = cb[0];
  const float4 iv = *(const float4*)(inp + (size_t)b * L_SEQ + l0);
  float4* dst = (float4*)(xp + (size_t)b * L_SEQ + l0);
  dst[0] = make_float4(acc.x + bias, iv.x, acc.y + bias, iv.y);
  dst[1] = make_float4(acc.z + bias, iv.z, acc.w + bias, iv.w);
}

// ---------------- Kernel 2: LSTM scan, 512 thr (8 waves, 2/SIMD) ----------------
__global__ __launch_bounds__(512, 1) void lstm_seq(
    const float2* __restrict__ xp, const float* __restrict__ wbuf,
    float* __restrict__ ssb, float* __restrict__ part) {
  __shared__ float2 sx[NB][WIN];          // 32.3 KB
  __shared__ float hb[2][NB][BLK_EMIT];   // 30.7 KB

  const int tid = threadIdx.x;
  const int wv = tid >> 6;        // wave 0..7
  const int lane = tid & 63;
  const int b = lane >> 3;        // batch
  const int q = lane & 7;         // slot within wave
  const int d = wv >> 2;          // direction
  const int u = wv & 3;           // sub-wave within direction 0..3
  const bool d0 = (d == 0);

  const int A = blockIdx.x * BLK_EMIT;   // block emit window [A, A+480)
  const int wbase = A - WARM - 2;        // shared window start

  // ---- stage shared window (512-lane cooperative, clamped) ----
#pragma unroll 2
  for (int idx = tid; idx < NB * WIN; idx += 512) {
    int bb = idx / WIN, ii = idx - bb * WIN;
    int l = wbase + ii;
    l = l < 0 ? 0 : (l > L_SEQ - 1 ? L_SEQ - 1 : l);
    sx[bb][ii] = xp[(size_t)bb * L_SEQ + l];
  }

  // ---- packed-weight preamble: one contiguous region, no transforms ----
  v2f wIF0[HID], wIF1[HID], bIF[HID], uIF[HID];
  v2f wGO0[HID], wGO1[HID], bGO[HID], uGO[HID];
  float wr[HID];
  {
    const v2f* wd = (const v2f*)wbuf + d * 40;
#pragma unroll
    for (int m = 0; m < HID; ++m) {
      wIF0[m] = wd[m];       wIF1[m] = wd[5 + m];
      bIF[m]  = wd[10 + m];  uIF[m]  = wd[15 + m];
      wGO0[m] = wd[20 + m];  wGO1[m] = wd[25 + m];
      bGO[m]  = wd[30 + m];  uGO[m]  = wd[35 + m];
      wr[m]   = wbuf[WB_WR + d * 5 + m];
    }
  }
  __syncthreads();

  // ---- per-lane chain geometry ----
  const int ci = u * 8 + q;               // chunk index within block+dir, 0..31
  const int a = A + ci * CHUNK;           // emit [a, a+15)
  int s0 = d0 ? (a - WARM) : (a + CHUNK - 1 + WARM);
  const bool exact = d0 ? (s0 <= 0) : (s0 >= L_SEQ - 1);
  int s0c = s0 < 0 ? 0 : (s0 > L_SEQ - 1 ? L_SEQ - 1 : s0);
  const int off0 = s0c - wbase;           // LDS start index (in [0, WIN))
  const int dl = d0 ? 1 : -1;
  int e = s0c - a;                        // emit index; advances by dl
  float* hrow = &hb[d][b][ci * CHUNK];

  float h = exact ? wbuf[WB_H0 + d * NB + b] : 0.0f;
  float c[HID];   // pre-scaled by NT2E (done in prepack)
#pragma unroll
  for (int m = 0; m < HID; ++m)
    c[m] = exact ? wbuf[WB_C0 + (d * NB + b) * HID + m] : 0.0f;

  // ---- prime: x(0) pre-activations (x-part only), x(1) in xN ----
  v2f preIF[HID], preGO[HID];
  {
    float2 x0 = sx[b][off0];
    v2f yy = {x0.x, x0.x}, zz = {x0.y, x0.y};
#pragma unroll
    for (int m = 0; m < HID; ++m) {
      preIF[m] = fma2(wIF0[m], yy, fma2(wIF1[m], zz, bIF[m]));
      preGO[m] = fma2(wGO0[m], yy, fma2(wGO1[m], zz, bGO[m]));
    }
  }
  float2 xN = sx[b][off0 + dl];
  int off = off0 + 2 * dl;

#pragma clang loop unroll(disable)
  for (int it = 0; it < MAXS; ++it) {
    // ---- h-part completes step-t gate pre-activations ----
    v2f hh = {h, h};
    v2f pIF[HID], pGO[HID];
#pragma unroll
    for (int m = 0; m < HID; ++m) {
      pIF[m] = fma2(uIF[m], hh, preIF[m]);
      pGO[m] = fma2(uGO[m], hh, preGO[m]);
    }
    // ---- next-step x-part (h-independent; fills trans shadow) ----
    {
      v2f yy = {xN.x, xN.x}, zz = {xN.y, xN.y};
#pragma unroll
      for (int m = 0; m < HID; ++m) {
        preIF[m] = fma2(wIF0[m], yy, fma2(wIF1[m], zz, bIF[m]));
        preGO[m] = fma2(wGO0[m], yy, fma2(wGO1[m], zz, bGO[m]));
      }
    }
    xN = sx[b][off]; off += dl;

    // ---- gate exps ----
    float eI[HID], eF[HID], eG[HID], eO[HID];
#pragma unroll
    for (int m = 0; m < HID; ++m) {
      eI[m] = fast_exp2(pIF[m].x);
      eF[m] = fast_exp2(pIF[m].y);
      eG[m] = fast_exp2(pGO[m].x);
      eO[m] = fast_exp2(pGO[m].y);
    }
    // ---- denominators + shared rcp ----
    float m1[HID], aF[HID], aO[HID], rD[HID];
#pragma unroll
    for (int m = 0; m < HID; ++m) {
      float aI = 1.0f + eI[m];
      float aG = 1.0f + eG[m];
      aF[m] = 1.0f + eF[m];
      aO[m] = 1.0f + eO[m];
      m1[m] = aI * aG;
      rD[m] = fast_rcp(m1[m] * aF[m]);
    }
    // ---- c update (scaled by NT2E) + eC ----
    float eC[HID];
#pragma unroll
    for (int m = 0; m < HID; ++m) {
      float t = fmaf(-NT2E, eG[m], NT2E) * aF[m];
      c[m] = fmaf(c[m], m1[m], t) * rD[m];
      eC[m] = fast_exp2(c[m]);
    }
    // ---- output terms ----
    float hs = 0.0f;
#pragma unroll
    for (int m = 0; m < HID; ++m) {
      float aC = 1.0f + eC[m];
      float rOC = fast_rcp(aO[m] * aC);
      float nmr = fmaf(-wr[m], eC[m], wr[m]);   // wr*(1-eC)
      hs = fmaf(nmr, rOC, hs);                  // += wr*so*tanh(c)
    }
    h = hs;
    if ((unsigned)e < (unsigned)CHUNK) hrow[e] = h;
    e += dl;
  }

  __syncthreads();

  // ---- exp(ss) to ssb + per-(batch,block) partial sums ----
  {
    const int bb = tid >> 6;          // 0..7 (one full wave per batch)
    const int li = tid & 63;
    float psum = 0.0f;
#pragma unroll
    for (int k = 0; k < 8; ++k) {
      int lo = li + 64 * k;
      if (lo < BLK_EMIT) {
        float pv = fast_exp(hb[0][bb][lo] + hb[1][bb][lo]);
        ssb[(size_t)bb * L_SEQ + A + lo] = pv;
        psum += pv;
      }
    }
    for (int o = 32; o > 0; o >>= 1) psum += __shfl_xor(psum, o, 64);
    if (li == 0) part[bb * NBLK + blockIdx.x] = psum;
  }
}

// ---------------- Kernel 3: inline finalize + write softmax ----------------
__global__ __launch_bounds__(256) void softmax_write(
    const float* __restrict__ ssb, const float* __restrict__ part,
    float2* __restrict__ out2) {
  __shared__ float zs[NB];
  const int tid = threadIdx.x;
  {
    const int g = tid >> 5;     // batch group 0..7
    const int i = tid & 31;
    float v = 0.0f;
    for (int k = i; k < NBLK; k += 32) v += part[g * NBLK + k];
    for (int o = 16; o > 0; o >>= 1) v += __shfl_xor(v, o, 64);
    if (i == 0) zs[g] = 1.0f / v;
  }
  __syncthreads();
  int idx = blockIdx.x * 256 + tid;
  int b = idx / L_SEQ;
  float pv = ssb[idx] * zs[b];
  out2[idx] = make_float2(pv, pv);
}

extern "C" void kernel_launch(void* const* d_in, const int* in_sizes, int n_in,
                              void* d_out, int out_size, void* d_ws, size_t ws_size,
                              hipStream_t stream) {
  const float* x     = (const float*)d_in[0];
  const float* inp   = (const float*)d_in[1];
  const float* cw    = (const float*)d_in[2];
  const float* cb    = (const float*)d_in[3];
  const float* wih_f = (const float*)d_in[4];
  const float* whh_f = (const float*)d_in[5];
  const float* bih_f = (const float*)d_in[6];
  const float* bhh_f = (const float*)d_in[7];
  const float* whr_f = (const float*)d_in[8];
  const float* wih_b = (const float*)d_in[9];
  const float* whh_b = (const float*)d_in[10];
  const float* bih_b = (const float*)d_in[11];
  const float* bhh_b = (const float*)d_in[12];
  const float* whr_b = (const float*)d_in[13];
  const float* h0    = (const float*)d_in[14];
  const float* c0    = (const float*)d_in[15];
  float2* out2 = (float2*)d_out;

  float2* xp  = (float2*)d_ws;                               // 3.84 MB
  float* ssb  = (float*)(xp + (size_t)NB * L_SEQ);           // 1.92 MB
  float* part = ssb + (size_t)NB * L_SEQ;                    // 4 KB
  float* wbuf = part + NB * NBLK;                            // ~1.1 KB

  conv_pack<<<(NB * (L_SEQ / 4) + 255) / 256, 256, 0, stream>>>(
      x, inp, cw, cb,
      wih_f, whh_f, bih_f, bhh_f, whr_f,
      wih_b, whh_b, bih_b, bhh_b, whr_b,
      h0, c0, xp, wbuf);
  lstm_seq<<<NBLK, 512, 0, stream>>>(xp, wbuf, ssb, part);
  softmax_write<<<(NB * L_SEQ) / 256, 256, 0, stream>>>(ssb, part, out2);
}

// Round 18
// 41.701 us; speedup vs baseline: 1.0973x; 1.0973x over previous
//
#include <hip/hip_runtime.h>

// OutConv_lstm: 1x1 conv (64ch -> 1) -> bidirectional projected LSTM (HID=5, PROJ=1)
// -> ss = hf+hb -> softmax over seq dim (both output channels identical since
// channel-1 logits are ss-1, a constant shift along the softmax axis).
//
// R18 = R16 revert (R17's 125x512 geometry left half the CUs idle: REJECTED)
// + pk-packed phase-3 adds (v_pk_add_f32, bit-identical arithmetic).
//  K1 conv_pack (wide, 469 blocks, L3-BW streaming) + block-0 prepack of
//     transformed weights/h0/c0*NT2E into one contiguous wbuf.
//  K2 lstm_seq (250x256, 1 wave/SIMD): stage window->LDS, WARM=8 scan
//     (23 steps, one chain/lane, phase-sorted, 8 trans/step, pipelined
//     x-part), exp(ss)->ssb + per-(batch,block) partials.
//  K3 softmax_write: inline redundant finalize (8KB L2-hot) + write.
// Ledger: conv ~13 (L3 BW floor) + lstm ~20 (ramp 7 + scan 7.5 + base) +
// write ~3 + gaps ~3. Geometry optimum is flat (NBLK 208 vs 250 < 0.3us).

#define L_SEQ 60000
#define NB 8
#define NCH 64
#define HID 5
#define CHUNK 15
#define WARM 8
#define MAXS (WARM + CHUNK)            // 23 iterations
#define BLK_EMIT 240                   // emit span per dir per block
#define NBLK (L_SEQ / BLK_EMIT)        // 250 blocks
#define WIN 264                        // LDS window (max index used 257)
// wbuf layout (floats): [0..159] v2f weights dir0|dir1 (40 v2f each)
//                       [160..169] wr_f|wr_b  [170..185] h0  [186..265] c0*NT2E
#define WB_WR 160
#define WB_H0 170
#define WB_C0 186

typedef __attribute__((ext_vector_type(2))) float v2f;

__device__ __forceinline__ float fast_exp2(float x) { return __builtin_amdgcn_exp2f(x); }
__device__ __forceinline__ float fast_rcp(float x) { return __builtin_amdgcn_rcpf(x); }
__device__ __forceinline__ float fast_exp(float x) {
  return __builtin_amdgcn_exp2f(x * 1.4426950408889634f);
}
__device__ __forceinline__ v2f fma2(v2f a, v2f b, v2f c) {
  return __builtin_elementwise_fma(a, b, c);
}

#define NL2E (-1.4426950408889634f)   // -log2(e): sigmoid gates
#define NT2E (-2.8853900817779268f)   // -2*log2(e): tanh args

// ---------------- Kernel 1: 1x1 conv + pack + weight prepack ----------------
__global__ __launch_bounds__(256) void conv_pack(
    const float* __restrict__ x, const float* __restrict__ inp,
    const float* __restrict__ cw, const float* __restrict__ cb,
    const float* __restrict__ wih_f, const float* __restrict__ whh_f,
    const float* __restrict__ bih_f, const float* __restrict__ bhh_f,
    const float* __restrict__ whr_f,
    const float* __restrict__ wih_b, const float* __restrict__ whh_b,
    const float* __restrict__ bih_b, const float* __restrict__ bhh_b,
    const float* __restrict__ whr_b,
    const float* __restrict__ h0, const float* __restrict__ c0,
    float2* __restrict__ xp, float* __restrict__ wbuf) {
  // ---- weight/state prepack (block 0 only; disjoint lanes) ----
  if (blockIdx.x == 0) {
    int t = threadIdx.x;
    if (t < 10) {
      int dd = t / 5, m = t - dd * 5;
      const float* wih = dd ? wih_b : wih_f;
      const float* whh = dd ? whh_b : whh_f;
      const float* bih = dd ? bih_b : bih_f;
      const float* bhh = dd ? bhh_b : bhh_f;
      const float* whr = dd ? whr_b : whr_f;
      const int ki = m, kf = 5 + m, kg = 10 + m, ko = 15 + m;
      float2* wd = (float2*)wbuf + dd * 40;
      wd[m]      = make_float2(wih[2 * ki] * NL2E, wih[2 * kf] * NL2E);
      wd[5 + m]  = make_float2(wih[2 * ki + 1] * NL2E, wih[2 * kf + 1] * NL2E);
      wd[10 + m] = make_float2((bih[ki] + bhh[ki]) * NL2E, (bih[kf] + bhh[kf]) * NL2E);
      wd[15 + m] = make_float2(whh[ki] * NL2E, whh[kf] * NL2E);
      wd[20 + m] = make_float2(wih[2 * kg] * NT2E, wih[2 * ko] * NL2E);
      wd[25 + m] = make_float2(wih[2 * kg + 1] * NT2E, wih[2 * ko + 1] * NL2E);
      wd[30 + m] = make_float2((bih[kg] + bhh[kg]) * NT2E, (bih[ko] + bhh[ko]) * NL2E);
      wd[35 + m] = make_float2(whh[kg] * NT2E, whh[ko] * NL2E);
      wbuf[WB_WR + dd * 5 + m] = whr[m];
    } else if (t >= 16 && t < 32) {
      wbuf[WB_H0 + (t - 16)] = h0[t - 16];
    } else if (t >= 32 && t < 112) {
      int i = t - 32;                      // i = (d*NB+b)*HID+m, 0..79
      wbuf[WB_C0 + i] = c0[i] * NT2E;
    }
  }
  // ---- conv main (wide) ----
  int tid = blockIdx.x * 256 + threadIdx.x;
  const int perb = L_SEQ / 4;
  if (tid >= NB * perb) return;
  int b = tid / perb;
  int l0 = (tid - b * perb) * 4;
  const float* xb = x + (size_t)b * NCH * L_SEQ + l0;
  float4 acc = make_float4(0.f, 0.f, 0.f, 0.f);
#pragma unroll 8
  for (int ch = 0; ch < NCH; ++ch) {
    float w = cw[ch];
    const float4 xv = *(const float4*)(xb + (size_t)ch * L_SEQ);
    acc.x = fmaf(w, xv.x, acc.x);
    acc.y = fmaf(w, xv.y, acc.y);
    acc.z = fmaf(w, xv.z, acc.z);
    acc.w = fmaf(w, xv.w, acc.w);
  }
  float bias = cb[0];
  const float4 iv = *(const float4*)(inp + (size_t)b * L_SEQ + l0);
  float4* dst = (float4*)(xp + (size_t)b * L_SEQ + l0);
  dst[0] = make_float4(acc.x + bias, iv.x, acc.y + bias, iv.y);
  dst[1] = make_float4(acc.z + bias, iv.z, acc.w + bias, iv.w);
}

// ---------------- Kernel 2: LSTM scan (packed weights) ----------------
__global__ __launch_bounds__(256, 1) void lstm_seq(
    const float2* __restrict__ xp, const float* __restrict__ wbuf,
    float* __restrict__ ssb, float* __restrict__ part) {
  __shared__ float2 sx[NB][WIN];          // 16.9 KB
  __shared__ float hb[2][NB][BLK_EMIT];   // 15.4 KB

  const int tid = threadIdx.x;
  const int wv = tid >> 6;        // wave 0..3
  const int lane = tid & 63;
  const int b = lane >> 3;        // batch
  const int q = lane & 7;         // slot within wave
  const int d = wv >> 1;          // direction
  const int u = wv & 1;           // sub-wave within direction
  const bool d0 = (d == 0);

  const int A = blockIdx.x * BLK_EMIT;   // block emit window [A, A+240)
  const int wbase = A - WARM - 2;        // shared window start

  // ---- stage shared window (256-lane cooperative, clamped) ----
#pragma unroll 3
  for (int idx = tid; idx < NB * WIN; idx += 256) {
    int bb = idx / WIN, ii = idx - bb * WIN;
    int l = wbase + ii;
    l = l < 0 ? 0 : (l > L_SEQ - 1 ? L_SEQ - 1 : l);
    sx[bb][ii] = xp[(size_t)bb * L_SEQ + l];
  }

  // ---- packed-weight preamble: one contiguous region, no transforms ----
  v2f wIF0[HID], wIF1[HID], bIF[HID], uIF[HID];
  v2f wGO0[HID], wGO1[HID], bGO[HID], uGO[HID];
  float wr[HID];
  {
    const v2f* wd = (const v2f*)wbuf + d * 40;
#pragma unroll
    for (int m = 0; m < HID; ++m) {
      wIF0[m] = wd[m];       wIF1[m] = wd[5 + m];
      bIF[m]  = wd[10 + m];  uIF[m]  = wd[15 + m];
      wGO0[m] = wd[20 + m];  wGO1[m] = wd[25 + m];
      bGO[m]  = wd[30 + m];  uGO[m]  = wd[35 + m];
      wr[m]   = wbuf[WB_WR + d * 5 + m];
    }
  }
  __syncthreads();

  // ---- per-lane chain geometry ----
  const int ci = u * 8 + q;               // chunk index within block+dir, 0..15
  const int a = A + ci * CHUNK;           // emit [a, a+15)
  int s0 = d0 ? (a - WARM) : (a + CHUNK - 1 + WARM);
  const bool exact = d0 ? (s0 <= 0) : (s0 >= L_SEQ - 1);
  int s0c = s0 < 0 ? 0 : (s0 > L_SEQ - 1 ? L_SEQ - 1 : s0);
  const int off0 = s0c - wbase;           // LDS start index (in [0, WIN))
  const int dl = d0 ? 1 : -1;
  int e = s0c - a;                        // emit index; advances by dl
  float* hrow = &hb[d][b][ci * CHUNK];

  float h = exact ? wbuf[WB_H0 + d * NB + b] : 0.0f;
  float c[HID];   // pre-scaled by NT2E (done in prepack)
#pragma unroll
  for (int m = 0; m < HID; ++m)
    c[m] = exact ? wbuf[WB_C0 + (d * NB + b) * HID + m] : 0.0f;

  // ---- prime: x(0) pre-activations (x-part only), x(1) in xN ----
  v2f preIF[HID], preGO[HID];
  {
    float2 x0 = sx[b][off0];
    v2f yy = {x0.x, x0.x}, zz = {x0.y, x0.y};
#pragma unroll
    for (int m = 0; m < HID; ++m) {
      preIF[m] = fma2(wIF0[m], yy, fma2(wIF1[m], zz, bIF[m]));
      preGO[m] = fma2(wGO0[m], yy, fma2(wGO1[m], zz, bGO[m]));
    }
  }
  float2 xN = sx[b][off0 + dl];
  int off = off0 + 2 * dl;

  const v2f one2 = {1.0f, 1.0f};

#pragma clang loop unroll(disable)
  for (int it = 0; it < MAXS; ++it) {
    // ---- h-part completes step-t gate pre-activations ----
    v2f hh = {h, h};
    v2f pIF[HID], pGO[HID];
#pragma unroll
    for (int m = 0; m < HID; ++m) {
      pIF[m] = fma2(uIF[m], hh, preIF[m]);
      pGO[m] = fma2(uGO[m], hh, preGO[m]);
    }
    // ---- next-step x-part (h-independent; fills trans shadow) ----
    {
      v2f yy = {xN.x, xN.x}, zz = {xN.y, xN.y};
#pragma unroll
      for (int m = 0; m < HID; ++m) {
        preIF[m] = fma2(wIF0[m], yy, fma2(wIF1[m], zz, bIF[m]));
        preGO[m] = fma2(wGO0[m], yy, fma2(wGO1[m], zz, bGO[m]));
      }
    }
    xN = sx[b][off]; off += dl;

    // ---- gate exps (scalar trans) packed into v2f pairs ----
    v2f eIG[HID], eFO[HID];   // {e^-i, e^-2g}, {e^-f, e^-o}
#pragma unroll
    for (int m = 0; m < HID; ++m) {
      eIG[m] = v2f{fast_exp2(pIF[m].x), fast_exp2(pGO[m].x)};
      eFO[m] = v2f{fast_exp2(pIF[m].y), fast_exp2(pGO[m].y)};
    }
    // ---- denominators (pk adds) + shared rcp ----
    float m1[HID], aF[HID], aO[HID], rD[HID], eG[HID];
#pragma unroll
    for (int m = 0; m < HID; ++m) {
      v2f aIG = eIG[m] + one2;           // v_pk_add_f32
      v2f aFO = eFO[m] + one2;           // v_pk_add_f32
      eG[m] = eIG[m].y;
      m1[m] = aIG.x * aIG.y;
      aF[m] = aFO.x;
      aO[m] = aFO.y;
      rD[m] = fast_rcp(m1[m] * aF[m]);
    }
    // ---- c update (scaled by NT2E) + eC ----
    float eC[HID];
#pragma unroll
    for (int m = 0; m < HID; ++m) {
      float t = fmaf(-NT2E, eG[m], NT2E) * aF[m];
      c[m] = fmaf(c[m], m1[m], t) * rD[m];
      eC[m] = fast_exp2(c[m]);
    }
    // ---- output terms ----
    float hs = 0.0f;
#pragma unroll
    for (int m = 0; m < HID; ++m) {
      float aC = 1.0f + eC[m];
      float rOC = fast_rcp(aO[m] * aC);
      float nmr = fmaf(-wr[m], eC[m], wr[m]);   // wr*(1-eC)
      hs = fmaf(nmr, rOC, hs);                  // += wr*so*tanh(c)
    }
    h = hs;
    if ((unsigned)e < (unsigned)CHUNK) hrow[e] = h;
    e += dl;
  }

  __syncthreads();

  // ---- exp(ss) to ssb + per-(batch,block) partial sums ----
  {
    const int bb = tid >> 5;          // 0..7 (32 threads per batch)
    const int li = tid & 31;
    float psum = 0.0f;
#pragma unroll
    for (int k = 0; k < 8; ++k) {
      int lo = li + 32 * k;
      if (lo < BLK_EMIT) {
        float pv = fast_exp(hb[0][bb][lo] + hb[1][bb][lo]);
        ssb[(size_t)bb * L_SEQ + A + lo] = pv;
        psum += pv;
      }
    }
    for (int o = 16; o > 0; o >>= 1) psum += __shfl_xor(psum, o, 64);
    if (li == 0) part[bb * NBLK + blockIdx.x] = psum;
  }
}

// ---------------- Kernel 3: inline finalize + write softmax ----------------
__global__ __launch_bounds__(256) void softmax_write(
    const float* __restrict__ ssb, const float* __restrict__ part,
    float2* __restrict__ out2) {
  __shared__ float zs[NB];
  const int tid = threadIdx.x;
  {
    const int g = tid >> 5;     // batch group 0..7
    const int i = tid & 31;
    float v = 0.0f;
    for (int k = i; k < NBLK; k += 32) v += part[g * NBLK + k];
    for (int o = 16; o > 0; o >>= 1) v += __shfl_xor(v, o, 64);
    if (i == 0) zs[g] = 1.0f / v;
  }
  __syncthreads();
  int idx = blockIdx.x * 256 + tid;
  int b = idx / L_SEQ;
  float pv = ssb[idx] * zs[b];
  out2[idx] = make_float2(pv, pv);
}

extern "C" void kernel_launch(void* const* d_in, const int* in_sizes, int n_in,
                              void* d_out, int out_size, void* d_ws, size_t ws_size,
                              hipStream_t stream) {
  const float* x     = (const float*)d_in[0];
  const float* inp   = (const float*)d_in[1];
  const float* cw    = (const float*)d_in[2];
  const float* cb    = (const float*)d_in[3];
  const float* wih_f = (const float*)d_in[4];
  const float* whh_f = (const float*)d_in[5];
  const float* bih_f = (const float*)d_in[6];
  const float* bhh_f = (const float*)d_in[7];
  const float* whr_f = (const float*)d_in[8];
  const float* wih_b = (const float*)d_in[9];
  const float* whh_b = (const float*)d_in[10];
  const float* bih_b = (const float*)d_in[11];
  const float* bhh_b = (const float*)d_in[12];
  const float* whr_b = (const float*)d_in[13];
  const float* h0    = (const float*)d_in[14];
  const float* c0    = (const float*)d_in[15];
  float2* out2 = (float2*)d_out;

  float2* xp  = (float2*)d_ws;                               // 3.84 MB
  float* ssb  = (float*)(xp + (size_t)NB * L_SEQ);           // 1.92 MB
  float* part = ssb + (size_t)NB * L_SEQ;                    // 8 KB
  float* wbuf = part + NB * NBLK;                            // ~1.1 KB

  conv_pack<<<(NB * (L_SEQ / 4) + 255) / 256, 256, 0, stream>>>(
      x, inp, cw, cb,
      wih_f, whh_f, bih_f, bhh_f, whr_f,
      wih_b, whh_b, bih_b, bhh_b, whr_b,
      h0, c0, xp, wbuf);
  lstm_seq<<<NBLK, 256, 0, stream>>>(xp, wbuf, ssb, part);
  softmax_write<<<(NB * L_SEQ) / 256, 256, 0, stream>>>(ssb, part, out2);
}